// Round 4
// baseline (1417.359 us; speedup 1.0000x reference)
//
#include <hip/hip_runtime.h>
#include <hip/hip_bf16.h>
#include <math.h>

namespace {

typedef __hip_bfloat16 bf16;

constexpr int Bb = 2;
constexpr int Ll = 2048;
constexpr int DM = 768;
constexpr int DI = 1536;          // 2*768
constexpr int DS = 16;
constexpr int RK = 48;
constexpr int XD = RK + 2 * DS;   // 80
constexpr int Mrows = Bb * Ll;    // 4096

__device__ inline float b2f(bf16 v) { return __bfloat162float(v); }
__device__ inline bf16 f2b(float v) { return __float2bfloat16(v); }

// Load element i of an EXTERNAL input tensor (dtype runtime-detected).
__device__ inline float ldx(const void* p, size_t i, int bf) {
  if (bf) return __bfloat162float(((const bf16*)p)[i]);
  return ((const float*)p)[i];
}

// ---- dtype probe: do low 16 bits of words look like bf16 values? ----
// f32 N(0,1) data: low 16 bits are uniform mantissa -> ~13% plausible.
// bf16 pairs: low half is a bf16 with exponent near 127 -> ~100% plausible.
__global__ void detect_kernel(const unsigned int* __restrict__ xw,
                              int* __restrict__ flag) {
  int t = threadIdx.x;  // 64 lanes
  unsigned int w = xw[t];
  unsigned int lo = w & 0xFFFFu;
  unsigned int ef = (lo >> 7) & 0xFFu;
  bool plaus = (lo == 0u) || (ef >= 104u && ef <= 136u);
  unsigned long long m = __ballot(plaus);
  if (t == 0) flag[0] = (__popcll(m) >= 48) ? 1 : 0;
}

// ---------------- LayerNorm: one block per row of 768, bf16 out -------
__global__ __launch_bounds__(256) void ln_kernel(
    const void* __restrict__ x, const void* __restrict__ w,
    const void* __restrict__ b, bf16* __restrict__ xn,
    const int* __restrict__ flagp) {
  int bf = flagp[0];
  int row = blockIdx.x;
  int t = threadIdx.x;
  float v[3];
  float s = 0.f, ss = 0.f;
#pragma unroll
  for (int i = 0; i < 3; ++i) {
    v[i] = ldx(x, (size_t)row * DM + t + i * 256, bf);
    s += v[i];
    ss += v[i] * v[i];
  }
#pragma unroll
  for (int off = 32; off; off >>= 1) {
    s += __shfl_down(s, off);
    ss += __shfl_down(ss, off);
  }
  __shared__ float sb[4], ssb[4];
  int wid = t >> 6, lid = t & 63;
  if (lid == 0) { sb[wid] = s; ssb[wid] = ss; }
  __syncthreads();
  if (t == 0) {
    sb[0] = sb[0] + sb[1] + sb[2] + sb[3];
    ssb[0] = ssb[0] + ssb[1] + ssb[2] + ssb[3];
  }
  __syncthreads();
  float mu = sb[0] * (1.f / DM);
  float var = ssb[0] * (1.f / DM) - mu * mu;
  float rs = rsqrtf(var + 1e-5f);
#pragma unroll
  for (int i = 0; i < 3; ++i) {
    int c = t + i * 256;
    xn[(size_t)row * DM + c] =
        f2b((v[i] - mu) * rs * ldx(w, c, bf) + ldx(b, c, bf));
  }
}

// ---- GEMM: C[M,N] = A[M,K](bf16 internal) * B[N,K](external)^T --------
// boff = element offset into Bw.
// EPI: 1 = softplus(acc + bias[n]) -> bf16;
//      2 = acc + resid[m*ldc+n] -> FLOAT out; 3 = plain bf16 store.
template <int EPI>
__global__ __launch_bounds__(256) void gemm_nt(
    int M, int N, int K,
    const bf16* __restrict__ A, int lda,
    const void* __restrict__ Bw, int ldb, size_t boff,
    void* __restrict__ Cv, int ldc,
    const void* __restrict__ extra,
    const int* __restrict__ flagp) {
  int bf = flagp[0];
  constexpr int BM = 64, BN = 64, BK = 16;
  __shared__ float As[BK][BM + 4];
  __shared__ float Bs[BK][BN + 4];
  int tid = threadIdx.x;
  int tx = tid & 15, ty = tid >> 4;
  int m0 = blockIdx.y * BM, n0 = blockIdx.x * BN;
  int lr = tid >> 2;           // 0..63, tile row
  int lk = (tid & 3) * 4;      // k sub-offset 0,4,8,12
  float acc[4][4] = {};
  for (int k0 = 0; k0 < K; k0 += BK) {
    int am = m0 + lr;
    float a0 = 0, a1 = 0, a2 = 0, a3 = 0;
    if (am < M) {
      const bf16* Ap = A + (size_t)am * lda + k0 + lk;
      a0 = b2f(Ap[0]); a1 = b2f(Ap[1]); a2 = b2f(Ap[2]); a3 = b2f(Ap[3]);
    }
    As[lk + 0][lr] = a0; As[lk + 1][lr] = a1;
    As[lk + 2][lr] = a2; As[lk + 3][lr] = a3;
    int bn = n0 + lr;
    float b0 = 0, b1 = 0, b2 = 0, b3 = 0;
    if (bn < N) {
      size_t bi = boff + (size_t)bn * ldb + k0 + lk;
      b0 = ldx(Bw, bi + 0, bf); b1 = ldx(Bw, bi + 1, bf);
      b2 = ldx(Bw, bi + 2, bf); b3 = ldx(Bw, bi + 3, bf);
    }
    Bs[lk + 0][lr] = b0; Bs[lk + 1][lr] = b1;
    Bs[lk + 2][lr] = b2; Bs[lk + 3][lr] = b3;
    __syncthreads();
#pragma unroll
    for (int kk = 0; kk < BK; ++kk) {
      float av[4], bv[4];
#pragma unroll
      for (int i = 0; i < 4; ++i) av[i] = As[kk][ty * 4 + i];
#pragma unroll
      for (int j = 0; j < 4; ++j) bv[j] = Bs[kk][tx * 4 + j];
#pragma unroll
      for (int i = 0; i < 4; ++i)
#pragma unroll
        for (int j = 0; j < 4; ++j) acc[i][j] += av[i] * bv[j];
    }
    __syncthreads();
  }
#pragma unroll
  for (int i = 0; i < 4; ++i) {
    int m = m0 + ty * 4 + i;
    if (m >= M) continue;
#pragma unroll
    for (int j = 0; j < 4; ++j) {
      int nn = n0 + tx * 4 + j;
      if (nn >= N) continue;
      float v = acc[i][j];
      size_t ci = (size_t)m * ldc + nn;
      if (EPI == 1) {
        float tt = v + ldx(extra, nn, bf);
        float sp = (tt > 20.f) ? tt : log1pf(__expf(tt));
        ((bf16*)Cv)[ci] = f2b(sp);
      } else if (EPI == 2) {
        // final output: FLOAT, + residual
        ((float*)Cv)[ci] = v + ldx(extra, ci, bf);
      } else {
        ((bf16*)Cv)[ci] = f2b(v);
      }
    }
  }
}

// ---------------- depthwise causal conv (d_conv=4) + bias + SiLU ------
__global__ __launch_bounds__(256) void conv_silu_kernel(
    const bf16* __restrict__ xin, const void* __restrict__ cw,
    const void* __restrict__ cb, bf16* __restrict__ xc,
    const int* __restrict__ flagp) {
  int bf = flagp[0];
  int idx = blockIdx.x * 256 + threadIdx.x;
  if (idx >= Mrows * DI) return;
  int d = idx % DI;
  int m = idx / DI;
  int l = m % Ll;
  float acc = ldx(cb, d, bf);
#pragma unroll
  for (int j = 0; j < 4; ++j) {
    int lj = l - 3 + j;
    if (lj >= 0)
      acc += ldx(cw, d * 4 + j, bf) * b2f(xin[(size_t)(m - 3 + j) * DI + d]);
  }
  xc[idx] = f2b(acc / (1.f + __expf(-acc)));
}

// ---------------- selective scan + skip + gating ----------------------
// dy: delta on input, y on output (in-place; per-element single-owner).
// block: 256 thr = 16 d x 16 n for one b; grid = Bb * DI/16 = 192
__global__ __launch_bounds__(256) void scan_kernel(
    bf16* dy, const bf16* __restrict__ xc,
    const bf16* __restrict__ xdbl, const bf16* __restrict__ z,
    const void* __restrict__ A_log, const void* __restrict__ Dp,
    const int* __restrict__ flagp) {
  int bf = flagp[0];
  int t = threadIdx.x;
  int n = t & 15, dl = t >> 4;
  int blk = blockIdx.x;
  int b = blk / (DI / 16);
  int d = (blk % (DI / 16)) * 16 + dl;
  float An = -__expf(ldx(A_log, d * DS + n, bf));
  float Dv = ldx(Dp, d, bf);
  float h = 0.f;
  size_t base = (size_t)b * Ll;
  for (int l0 = 0; l0 < Ll; l0 += 4) {
    float dv[4], xcv[4], Bv[4], Cv[4], zv[4];
#pragma unroll
    for (int j = 0; j < 4; ++j) {
      size_t row = base + l0 + j;
      dv[j] = b2f(dy[row * DI + d]);
      xcv[j] = b2f(xc[row * DI + d]);
      Bv[j] = b2f(xdbl[row * XD + RK + n]);
      Cv[j] = b2f(xdbl[row * XD + RK + DS + n]);
      zv[j] = b2f(z[row * DI + d]);
    }
#pragma unroll
    for (int j = 0; j < 4; ++j) {
      float dA = __expf(dv[j] * An);
      h = dA * h + dv[j] * Bv[j] * xcv[j];
      float contrib = h * Cv[j];
      contrib += __shfl_xor(contrib, 1, 16);
      contrib += __shfl_xor(contrib, 2, 16);
      contrib += __shfl_xor(contrib, 4, 16);
      contrib += __shfl_xor(contrib, 8, 16);
      if (n == 0) {
        float yv = (contrib + xcv[j] * Dv) * (zv[j] / (1.f + __expf(-zv[j])));
        dy[(base + l0 + j) * DI + d] = f2b(yv);
      }
    }
  }
}

}  // namespace

extern "C" void kernel_launch(void* const* d_in, const int* in_sizes, int n_in,
                              void* d_out, int out_size, void* d_ws, size_t ws_size,
                              hipStream_t stream) {
  const void* x        = d_in[0];
  const void* in_proj  = d_in[1];
  const void* conv_w   = d_in[2];
  const void* conv_b   = d_in[3];
  const void* x_proj   = d_in[4];
  const void* dt_proj  = d_in[5];
  const void* dt_b     = d_in[6];
  const void* A_log    = d_in[7];
  const void* Dp       = d_in[8];
  const void* out_proj = d_in[9];
  const void* ln_w     = d_in[10];
  const void* ln_b     = d_in[11];
  float* out = (float*)d_out;  // reference output dtype: float32

  // ws layout: flag (256B) + bf16 intermediates, total ~44.7 MB
  char* wsc = (char*)d_ws;
  int* flag = (int*)wsc;
  bf16* xn   = (bf16*)(wsc + 256);             // [4096,768]
  bf16* buf1 = xn + (size_t)Mrows * DM;        // [4096,1536]: xin -> delta -> y
  bf16* z    = buf1 + (size_t)Mrows * DI;      // [4096,1536]
  bf16* xc   = z + (size_t)Mrows * DI;         // [4096,1536]
  bf16* xdbl = xc + (size_t)Mrows * DI;        // [4096,80]

  // 0. detect input dtype (bf16 vs f32) from x's bit patterns
  detect_kernel<<<1, 64, 0, stream>>>((const unsigned int*)x, flag);
  // 1. layernorm -> xn (bf16)
  ln_kernel<<<Mrows, 256, 0, stream>>>(x, ln_w, ln_b, xn, flag);
  // 2a. xin = xn @ in_proj[0:DI]^T   -> buf1
  gemm_nt<3><<<dim3(DI / 64, Mrows / 64), 256, 0, stream>>>(
      Mrows, DI, DM, xn, DM, in_proj, DM, 0, buf1, DI, nullptr, flag);
  // 2b. z = xn @ in_proj[DI:2*DI]^T
  gemm_nt<3><<<dim3(DI / 64, Mrows / 64), 256, 0, stream>>>(
      Mrows, DI, DM, xn, DM, in_proj, DM, (size_t)DI * DM, z, DI, nullptr, flag);
  // 3. conv + silu: buf1(xin) -> xc
  conv_silu_kernel<<<(Mrows * DI) / 256, 256, 0, stream>>>(buf1, conv_w, conv_b, xc, flag);
  // 4. x_dbl = xc @ x_proj^T  [4096, 80]
  gemm_nt<3><<<dim3((XD + 63) / 64, Mrows / 64), 256, 0, stream>>>(
      Mrows, XD, DI, xc, DI, x_proj, DI, 0, xdbl, XD, nullptr, flag);
  // 5. delta = softplus(x_dbl[:, :48] @ dt_proj^T + dt_b) -> buf1 (xin dead)
  gemm_nt<1><<<dim3(DI / 64, Mrows / 64), 256, 0, stream>>>(
      Mrows, DI, RK, xdbl, XD, dt_proj, RK, 0, buf1, DI, dt_b, flag);
  // 6. selective scan + D skip + z gating: buf1(delta) -> buf1(y) in place
  scan_kernel<<<Bb * (DI / 16), 256, 0, stream>>>(buf1, xc, xdbl, z, A_log, Dp, flag);
  // 7. out = y @ out_proj^T + x (residual), FLOAT out
  gemm_nt<2><<<dim3(DM / 64, Mrows / 64), 256, 0, stream>>>(
      Mrows, DM, DI, buf1, DI, out_proj, DI, 0, out, DM, x, flag);
}

// Round 5
// 854.983 us; speedup vs baseline: 1.6578x; 1.6578x over previous
//
#include <hip/hip_runtime.h>
#include <hip/hip_bf16.h>
#include <math.h>

namespace {

typedef __hip_bfloat16 bf16;

constexpr int Bb = 2;
constexpr int Ll = 2048;
constexpr int DM = 768;
constexpr int DI = 1536;          // 2*768
constexpr int DS = 16;
constexpr int RK = 48;
constexpr int XD = RK + 2 * DS;   // 80
constexpr int Mrows = Bb * Ll;    // 4096
constexpr int NC = 32;            // scan chunks
constexpr int CL = Ll / NC;       // 64 steps per chunk
constexpr int NDB = DI / 16;      // 96 d-blocks

__device__ inline float b2f(bf16 v) { return __bfloat162float(v); }
__device__ inline bf16 f2b(float v) { return __float2bfloat16(v); }

// Load element i of an EXTERNAL input tensor (dtype runtime-detected).
__device__ inline float ldx(const void* p, size_t i, int bf) {
  if (bf) return __bfloat162float(((const bf16*)p)[i]);
  return ((const float*)p)[i];
}

// ---- dtype probe: do low 16 bits of words look like bf16 values? ----
__global__ void detect_kernel(const unsigned int* __restrict__ xw,
                              int* __restrict__ flag) {
  int t = threadIdx.x;  // 64 lanes
  unsigned int w = xw[t];
  unsigned int lo = w & 0xFFFFu;
  unsigned int ef = (lo >> 7) & 0xFFu;
  bool plaus = (lo == 0u) || (ef >= 104u && ef <= 136u);
  unsigned long long m = __ballot(plaus);
  if (t == 0) flag[0] = (__popcll(m) >= 48) ? 1 : 0;
}

// ---------------- LayerNorm: one block per row of 768, bf16 out -------
__global__ __launch_bounds__(256) void ln_kernel(
    const void* __restrict__ x, const void* __restrict__ w,
    const void* __restrict__ b, bf16* __restrict__ xn,
    const int* __restrict__ flagp) {
  int bf = flagp[0];
  int row = blockIdx.x;
  int t = threadIdx.x;
  float v[3];
  float s = 0.f, ss = 0.f;
#pragma unroll
  for (int i = 0; i < 3; ++i) {
    v[i] = ldx(x, (size_t)row * DM + t + i * 256, bf);
    s += v[i];
    ss += v[i] * v[i];
  }
#pragma unroll
  for (int off = 32; off; off >>= 1) {
    s += __shfl_down(s, off);
    ss += __shfl_down(ss, off);
  }
  __shared__ float sb[4], ssb[4];
  int wid = t >> 6, lid = t & 63;
  if (lid == 0) { sb[wid] = s; ssb[wid] = ss; }
  __syncthreads();
  if (t == 0) {
    sb[0] = sb[0] + sb[1] + sb[2] + sb[3];
    ssb[0] = ssb[0] + ssb[1] + ssb[2] + ssb[3];
  }
  __syncthreads();
  float mu = sb[0] * (1.f / DM);
  float var = ssb[0] * (1.f / DM) - mu * mu;
  float rs = rsqrtf(var + 1e-5f);
#pragma unroll
  for (int i = 0; i < 3; ++i) {
    int c = t + i * 256;
    xn[(size_t)row * DM + c] =
        f2b((v[i] - mu) * rs * ldx(w, c, bf) + ldx(b, c, bf));
  }
}

// ---- GEMM: C[M,N] = A[M,K](bf16 internal) * B[N,K](external)^T --------
// EPI: 1 = softplus(acc + bias[n]) -> bf16;
//      2 = acc + resid[m*ldc+n] -> FLOAT out; 3 = plain bf16 store.
template <int EPI>
__global__ __launch_bounds__(256) void gemm_nt(
    int M, int N, int K,
    const bf16* __restrict__ A, int lda,
    const void* __restrict__ Bw, int ldb, size_t boff,
    void* __restrict__ Cv, int ldc,
    const void* __restrict__ extra,
    const int* __restrict__ flagp) {
  int bf = flagp[0];
  constexpr int BM = 64, BN = 64, BK = 16;
  __shared__ float As[BK][BM + 4];
  __shared__ float Bs[BK][BN + 4];
  int tid = threadIdx.x;
  int tx = tid & 15, ty = tid >> 4;
  int m0 = blockIdx.y * BM, n0 = blockIdx.x * BN;
  int lr = tid >> 2;           // 0..63, tile row
  int lk = (tid & 3) * 4;      // k sub-offset 0,4,8,12
  float acc[4][4] = {};
  for (int k0 = 0; k0 < K; k0 += BK) {
    int am = m0 + lr;
    float a0 = 0, a1 = 0, a2 = 0, a3 = 0;
    if (am < M) {
      const bf16* Ap = A + (size_t)am * lda + k0 + lk;
      a0 = b2f(Ap[0]); a1 = b2f(Ap[1]); a2 = b2f(Ap[2]); a3 = b2f(Ap[3]);
    }
    As[lk + 0][lr] = a0; As[lk + 1][lr] = a1;
    As[lk + 2][lr] = a2; As[lk + 3][lr] = a3;
    int bn = n0 + lr;
    float b0 = 0, b1 = 0, b2 = 0, b3 = 0;
    if (bn < N) {
      size_t bi = boff + (size_t)bn * ldb + k0 + lk;
      b0 = ldx(Bw, bi + 0, bf); b1 = ldx(Bw, bi + 1, bf);
      b2 = ldx(Bw, bi + 2, bf); b3 = ldx(Bw, bi + 3, bf);
    }
    Bs[lk + 0][lr] = b0; Bs[lk + 1][lr] = b1;
    Bs[lk + 2][lr] = b2; Bs[lk + 3][lr] = b3;
    __syncthreads();
#pragma unroll
    for (int kk = 0; kk < BK; ++kk) {
      float av[4], bv[4];
#pragma unroll
      for (int i = 0; i < 4; ++i) av[i] = As[kk][ty * 4 + i];
#pragma unroll
      for (int j = 0; j < 4; ++j) bv[j] = Bs[kk][tx * 4 + j];
#pragma unroll
      for (int i = 0; i < 4; ++i)
#pragma unroll
        for (int j = 0; j < 4; ++j) acc[i][j] += av[i] * bv[j];
    }
    __syncthreads();
  }
#pragma unroll
  for (int i = 0; i < 4; ++i) {
    int m = m0 + ty * 4 + i;
    if (m >= M) continue;
#pragma unroll
    for (int j = 0; j < 4; ++j) {
      int nn = n0 + tx * 4 + j;
      if (nn >= N) continue;
      float v = acc[i][j];
      size_t ci = (size_t)m * ldc + nn;
      if (EPI == 1) {
        float tt = v + ldx(extra, nn, bf);
        float sp = (tt > 20.f) ? tt : log1pf(__expf(tt));
        ((bf16*)Cv)[ci] = f2b(sp);
      } else if (EPI == 2) {
        ((float*)Cv)[ci] = v + ldx(extra, ci, bf);
      } else {
        ((bf16*)Cv)[ci] = f2b(v);
      }
    }
  }
}

// ---------------- depthwise causal conv (d_conv=4) + bias + SiLU ------
__global__ __launch_bounds__(256) void conv_silu_kernel(
    const bf16* __restrict__ xin, const void* __restrict__ cw,
    const void* __restrict__ cb, bf16* __restrict__ xc,
    const int* __restrict__ flagp) {
  int bf = flagp[0];
  int idx = blockIdx.x * 256 + threadIdx.x;
  if (idx >= Mrows * DI) return;
  int d = idx % DI;
  int m = idx / DI;
  int l = m % Ll;
  float acc = ldx(cb, d, bf);
#pragma unroll
  for (int j = 0; j < 4; ++j) {
    int lj = l - 3 + j;
    if (lj >= 0)
      acc += ldx(cw, d * 4 + j, bf) * b2f(xin[(size_t)(m - 3 + j) * DI + d]);
  }
  xc[idx] = f2b(acc / (1.f + __expf(-acc)));
}

// ====== chunked selective scan ======
// thread map (all phases): t = dl*16 + n; block.x = b*NDB + dblk.
// carry layout: [((b*NC + c)*NDB + dblk)*256 + t], f32.

// Phase 1: per-chunk local scan from h=0 -> (a = prod dA, b = h_local)
__global__ __launch_bounds__(256) void scan_p1(
    const bf16* __restrict__ delta, const bf16* __restrict__ xc,
    const bf16* __restrict__ xdbl, const void* __restrict__ A_log,
    float* __restrict__ ca, float* __restrict__ cb,
    const int* __restrict__ flagp) {
  int bf = flagp[0];
  int t = threadIdx.x;
  int n = t & 15, dl = t >> 4;
  int bx = blockIdx.x, c = blockIdx.y;
  int b = bx / NDB, dblk = bx % NDB;
  int d = dblk * 16 + dl;
  float An = -__expf(ldx(A_log, d * DS + n, bf));
  float h = 0.f, ap = 1.f;
  size_t base = (size_t)b * Ll + c * CL;
  for (int l0 = 0; l0 < CL; l0 += 4) {
    float dv[4], xcv[4], Bv[4];
#pragma unroll
    for (int j = 0; j < 4; ++j) {
      size_t row = base + l0 + j;
      dv[j] = b2f(delta[row * DI + d]);
      xcv[j] = b2f(xc[row * DI + d]);
      Bv[j] = b2f(xdbl[row * XD + RK + n]);
    }
#pragma unroll
    for (int j = 0; j < 4; ++j) {
      float dA = __expf(dv[j] * An);
      h = dA * h + dv[j] * Bv[j] * xcv[j];
      ap *= dA;
    }
  }
  size_t ci = ((size_t)(b * NC + c) * NDB + dblk) * 256 + t;
  ca[ci] = ap;
  cb[ci] = h;
}

// Phase 2: sequential scan over chunk carries -> h_init per chunk
// (overwrites cb[c] with h BEFORE chunk c).
__global__ __launch_bounds__(256) void scan_p2(
    const float* __restrict__ ca, float* __restrict__ cb) {
  int t = threadIdx.x;
  int bx = blockIdx.x;
  int b = bx / NDB, dblk = bx % NDB;
  size_t base = ((size_t)b * NC * NDB + dblk) * 256 + t;
  const size_t cs = (size_t)NDB * 256;
  float av[NC], bv[NC];
#pragma unroll
  for (int c = 0; c < NC; ++c) {
    av[c] = ca[base + c * cs];
    bv[c] = cb[base + c * cs];
  }
  float h = 0.f;
#pragma unroll
  for (int c = 0; c < NC; ++c) {
    cb[base + c * cs] = h;
    h = av[c] * h + bv[c];
  }
}

// Phase 3: recompute local scan from h_init, reduce over n, gate, emit y.
// dy: delta in, y out (in-place; each (row,d) owned by one 16-lane group).
__global__ __launch_bounds__(256) void scan_p3(
    bf16* dy, const bf16* __restrict__ xc,
    const bf16* __restrict__ xdbl, const bf16* __restrict__ z,
    const void* __restrict__ A_log, const void* __restrict__ Dp,
    const float* __restrict__ cb, const int* __restrict__ flagp) {
  int bf = flagp[0];
  int t = threadIdx.x;
  int n = t & 15, dl = t >> 4;
  int bx = blockIdx.x, c = blockIdx.y;
  int b = bx / NDB, dblk = bx % NDB;
  int d = dblk * 16 + dl;
  float An = -__expf(ldx(A_log, d * DS + n, bf));
  float Dv = ldx(Dp, d, bf);
  size_t ci = ((size_t)(b * NC + c) * NDB + dblk) * 256 + t;
  float h = cb[ci];
  size_t base = (size_t)b * Ll + c * CL;
  for (int l0 = 0; l0 < CL; l0 += 4) {
    float dv[4], xcv[4], Bv[4], Cv[4], zv[4];
#pragma unroll
    for (int j = 0; j < 4; ++j) {
      size_t row = base + l0 + j;
      dv[j] = b2f(dy[row * DI + d]);
      xcv[j] = b2f(xc[row * DI + d]);
      Bv[j] = b2f(xdbl[row * XD + RK + n]);
      Cv[j] = b2f(xdbl[row * XD + RK + DS + n]);
      zv[j] = b2f(z[row * DI + d]);
    }
#pragma unroll
    for (int j = 0; j < 4; ++j) {
      float dA = __expf(dv[j] * An);
      h = dA * h + dv[j] * Bv[j] * xcv[j];
      float contrib = h * Cv[j];
      contrib += __shfl_xor(contrib, 1, 16);
      contrib += __shfl_xor(contrib, 2, 16);
      contrib += __shfl_xor(contrib, 4, 16);
      contrib += __shfl_xor(contrib, 8, 16);
      if (n == 0) {
        float yv = (contrib + xcv[j] * Dv) * (zv[j] / (1.f + __expf(-zv[j])));
        dy[(base + l0 + j) * DI + d] = f2b(yv);
      }
    }
  }
}

}  // namespace

extern "C" void kernel_launch(void* const* d_in, const int* in_sizes, int n_in,
                              void* d_out, int out_size, void* d_ws, size_t ws_size,
                              hipStream_t stream) {
  const void* x        = d_in[0];
  const void* in_proj  = d_in[1];
  const void* conv_w   = d_in[2];
  const void* conv_b   = d_in[3];
  const void* x_proj   = d_in[4];
  const void* dt_proj  = d_in[5];
  const void* dt_b     = d_in[6];
  const void* A_log    = d_in[7];
  const void* Dp       = d_in[8];
  const void* out_proj = d_in[9];
  const void* ln_w     = d_in[10];
  const void* ln_b     = d_in[11];
  float* out = (float*)d_out;  // reference output dtype: float32

  // ws layout (~51 MB): flag | xn (reused as carry_a) | buf1 | z | xc | xdbl | carry_b
  char* wsc = (char*)d_ws;
  int* flag = (int*)wsc;
  bf16* xn   = (bf16*)(wsc + 256);             // [4096,768] bf16 = 6.29 MB
  bf16* buf1 = xn + (size_t)Mrows * DM;        // [4096,1536]: xin -> delta -> y
  bf16* z    = buf1 + (size_t)Mrows * DI;
  bf16* xc   = z + (size_t)Mrows * DI;
  bf16* xdbl = xc + (size_t)Mrows * DI;        // [4096,80]
  float* carry_b = (float*)(xdbl + (size_t)Mrows * XD);  // 6.29 MB f32
  float* carry_a = (float*)xn;  // xn dead after in_proj GEMMs; exact-size reuse

  // 0. detect input dtype (bf16 vs f32)
  detect_kernel<<<1, 64, 0, stream>>>((const unsigned int*)x, flag);
  // 1. layernorm -> xn (bf16)
  ln_kernel<<<Mrows, 256, 0, stream>>>(x, ln_w, ln_b, xn, flag);
  // 2a. xin = xn @ in_proj[0:DI]^T   -> buf1
  gemm_nt<3><<<dim3(DI / 64, Mrows / 64), 256, 0, stream>>>(
      Mrows, DI, DM, xn, DM, in_proj, DM, 0, buf1, DI, nullptr, flag);
  // 2b. z = xn @ in_proj[DI:2*DI]^T
  gemm_nt<3><<<dim3(DI / 64, Mrows / 64), 256, 0, stream>>>(
      Mrows, DI, DM, xn, DM, in_proj, DM, (size_t)DI * DM, z, DI, nullptr, flag);
  // 3. conv + silu: buf1(xin) -> xc
  conv_silu_kernel<<<(Mrows * DI) / 256, 256, 0, stream>>>(buf1, conv_w, conv_b, xc, flag);
  // 4. x_dbl = xc @ x_proj^T  [4096, 80]
  gemm_nt<3><<<dim3((XD + 63) / 64, Mrows / 64), 256, 0, stream>>>(
      Mrows, XD, DI, xc, DI, x_proj, DI, 0, xdbl, XD, nullptr, flag);
  // 5. delta = softplus(x_dbl[:, :48] @ dt_proj^T + dt_b) -> buf1
  gemm_nt<1><<<dim3(DI / 64, Mrows / 64), 256, 0, stream>>>(
      Mrows, DI, RK, xdbl, XD, dt_proj, RK, 0, buf1, DI, dt_b, flag);
  // 6. chunked selective scan (P1 local, P2 carry, P3 emit) in buf1
  scan_p1<<<dim3(Bb * NDB, NC), 256, 0, stream>>>(
      buf1, xc, xdbl, A_log, carry_a, carry_b, flag);
  scan_p2<<<Bb * NDB, 256, 0, stream>>>(carry_a, carry_b);
  scan_p3<<<dim3(Bb * NDB, NC), 256, 0, stream>>>(
      buf1, xc, xdbl, z, A_log, Dp, carry_b, flag);
  // 7. out = y @ out_proj^T + x (residual), FLOAT out
  gemm_nt<2><<<dim3(DM / 64, Mrows / 64), 256, 0, stream>>>(
      Mrows, DM, DI, buf1, DI, out_proj, DI, 0, out, DM, x, flag);
}

// Round 6
// 538.057 us; speedup vs baseline: 2.6342x; 1.5890x over previous
//
#include <hip/hip_runtime.h>
#include <hip/hip_bf16.h>
#include <math.h>

namespace {

typedef __hip_bfloat16 bf16;
typedef unsigned short u16;
typedef __bf16 bf8v __attribute__((ext_vector_type(8)));
typedef float f4v __attribute__((ext_vector_type(4)));
typedef short s8v __attribute__((ext_vector_type(8)));
typedef u16 u4v __attribute__((ext_vector_type(4)));

constexpr int Bb = 2;
constexpr int Ll = 2048;
constexpr int DM = 768;
constexpr int DI = 1536;          // 2*768
constexpr int DS = 16;
constexpr int RK = 48;
constexpr int XD = RK + 2 * DS;   // 80
constexpr int Mrows = Bb * Ll;    // 4096
constexpr int NC = 32;            // scan chunks
constexpr int CL = Ll / NC;       // 64 steps per chunk
constexpr int NDB = DI / 16;      // 96 d-blocks

__device__ inline float b2f(bf16 v) { return __bfloat162float(v); }
__device__ inline bf16 f2b(float v) { return __float2bfloat16(v); }

union BfBits { bf16 h; u16 u; };
__device__ inline u16 f2u(float v) {
  BfBits bb; bb.h = __float2bfloat16(v); return bb.u;
}

// Load element i of an EXTERNAL input tensor (dtype runtime-detected).
__device__ inline float ldx(const void* p, size_t i, int bf) {
  if (bf) return __bfloat162float(((const bf16*)p)[i]);
  return ((const float*)p)[i];
}

// ---- dtype probe: do low 16 bits of words look like bf16 values? ----
__global__ void detect_kernel(const unsigned int* __restrict__ xw,
                              int* __restrict__ flag) {
  int t = threadIdx.x;  // 64 lanes
  unsigned int w = xw[t];
  unsigned int lo = w & 0xFFFFu;
  unsigned int ef = (lo >> 7) & 0xFFu;
  bool plaus = (lo == 0u) || (ef >= 104u && ef <= 136u);
  unsigned long long m = __ballot(plaus);
  if (t == 0) flag[0] = (__popcll(m) >= 48) ? 1 : 0;
}

// ---------------- LayerNorm: one block per row of 768, bf16 out -------
__global__ __launch_bounds__(256) void ln_kernel(
    const void* __restrict__ x, const void* __restrict__ w,
    const void* __restrict__ b, bf16* __restrict__ xn,
    const int* __restrict__ flagp) {
  int bf = flagp[0];
  int row = blockIdx.x;
  int t = threadIdx.x;
  float v[3];
  float s = 0.f, ss = 0.f;
#pragma unroll
  for (int i = 0; i < 3; ++i) {
    v[i] = ldx(x, (size_t)row * DM + t + i * 256, bf);
    s += v[i];
    ss += v[i] * v[i];
  }
#pragma unroll
  for (int off = 32; off; off >>= 1) {
    s += __shfl_down(s, off);
    ss += __shfl_down(ss, off);
  }
  __shared__ float sb[4], ssb[4];
  int wid = t >> 6, lid = t & 63;
  if (lid == 0) { sb[wid] = s; ssb[wid] = ss; }
  __syncthreads();
  if (t == 0) {
    sb[0] = sb[0] + sb[1] + sb[2] + sb[3];
    ssb[0] = ssb[0] + ssb[1] + ssb[2] + ssb[3];
  }
  __syncthreads();
  float mu = sb[0] * (1.f / DM);
  float var = ssb[0] * (1.f / DM) - mu * mu;
  float rs = rsqrtf(var + 1e-5f);
#pragma unroll
  for (int i = 0; i < 3; ++i) {
    int c = t + i * 256;
    xn[(size_t)row * DM + c] =
        f2b((v[i] - mu) * rs * ldx(w, c, bf) + ldx(b, c, bf));
  }
}

// ---- MFMA GEMM: C[M,N] = A[M,K](bf16) * B[N,K](external)^T ----------
// 128x128 tile, BK=32, 4 waves (2x2), per-wave 4x4 frags of 16x16x32.
// EPI: 1 = softplus(acc + bias[n]) -> bf16;
//      2 = acc + resid[m*ldc+n] -> FLOAT out; 3 = plain bf16 store.
template <int EPI>
__global__ __launch_bounds__(256, 2) void gemm_mf(
    int M, int N, int K,
    const bf16* __restrict__ A, int lda,
    const void* __restrict__ Bw, int ldb, size_t boff,
    void* __restrict__ Cv, int ldc,
    const void* __restrict__ extra,
    const int* __restrict__ flagp) {
  int bf = flagp[0];
  constexpr int LDW = 40;  // padded row (elems): 80B stride, 16B-aligned
  __shared__ u16 As[128 * LDW];
  __shared__ u16 Bs[128 * LDW];
  int tid = threadIdx.x;
  int l = tid & 63, w = tid >> 6;
  int wr = w >> 1, wc = w & 1;
  int m0 = blockIdx.y * 128, n0 = blockIdx.x * 128;
  int lr = l & 15, lk = (l >> 4) * 8;
  f4v acc[4][4] = {};

  for (int k0 = 0; k0 < K; k0 += 32) {
    // stage A: 2 chunks of 8 bf16 per thread
#pragma unroll
    for (int c = 0; c < 2; ++c) {
      int row = (tid >> 2) + c * 64;
      int kc = (tid & 3) * 8;
      int gk = k0 + kc;
      s8v v = {};
      if (gk < K) v = *(const s8v*)(A + (size_t)(m0 + row) * lda + gk);
      *(s8v*)&As[row * LDW + kc] = v;
    }
    // stage B: 4 chunks of 4 elems per thread (f32->bf16 convert)
#pragma unroll
    for (int c = 0; c < 4; ++c) {
      int row = (tid >> 3) + c * 32;
      int q = (tid & 7) * 4;
      int gn = n0 + row, gk = k0 + q;
      u4v v = {};
      if (gn < N && gk < K) {
        size_t bi = boff + (size_t)gn * ldb + gk;
        if (!bf) {
          float4 f = *(const float4*)((const float*)Bw + bi);
          v[0] = f2u(f.x); v[1] = f2u(f.y); v[2] = f2u(f.z); v[3] = f2u(f.w);
        } else {
          const u16* up = (const u16*)Bw + bi;
          v[0] = up[0]; v[1] = up[1]; v[2] = up[2]; v[3] = up[3];
        }
      }
      *(u4v*)&Bs[row * LDW + q] = v;
    }
    __syncthreads();
    bf8v af[4], bfv[4];
#pragma unroll
    for (int i = 0; i < 4; ++i)
      af[i] = *(const bf8v*)&As[(wr * 64 + i * 16 + lr) * LDW + lk];
#pragma unroll
    for (int j = 0; j < 4; ++j)
      bfv[j] = *(const bf8v*)&Bs[(wc * 64 + j * 16 + lr) * LDW + lk];
#pragma unroll
    for (int i = 0; i < 4; ++i)
#pragma unroll
      for (int j = 0; j < 4; ++j)
        acc[i][j] = __builtin_amdgcn_mfma_f32_16x16x32_bf16(
            af[i], bfv[j], acc[i][j], 0, 0, 0);
    __syncthreads();
  }
  // epilogue: lane l covers col = ..+ (l&15), rows (l>>4)*4 + r
  int lq = l >> 4;
#pragma unroll
  for (int i = 0; i < 4; ++i) {
#pragma unroll
    for (int j = 0; j < 4; ++j) {
      int nn = n0 + wc * 64 + j * 16 + lr;
      if (nn >= N) continue;
#pragma unroll
      for (int r = 0; r < 4; ++r) {
        int m = m0 + wr * 64 + i * 16 + lq * 4 + r;
        float v = acc[i][j][r];
        size_t ci = (size_t)m * ldc + nn;
        if (EPI == 1) {
          float tt = v + ldx(extra, nn, bf);
          float sp = (tt > 20.f) ? tt : log1pf(__expf(tt));
          ((bf16*)Cv)[ci] = f2b(sp);
        } else if (EPI == 2) {
          ((float*)Cv)[ci] = v + ldx(extra, ci, bf);
        } else {
          ((bf16*)Cv)[ci] = f2b(v);
        }
      }
    }
  }
}

// ---------------- depthwise causal conv (d_conv=4) + bias + SiLU ------
__global__ __launch_bounds__(256) void conv_silu_kernel(
    const bf16* __restrict__ xin, const void* __restrict__ cw,
    const void* __restrict__ cb, bf16* __restrict__ xc,
    const int* __restrict__ flagp) {
  int bf = flagp[0];
  int idx = blockIdx.x * 256 + threadIdx.x;
  if (idx >= Mrows * DI) return;
  int d = idx % DI;
  int m = idx / DI;
  int l = m % Ll;
  float acc = ldx(cb, d, bf);
#pragma unroll
  for (int j = 0; j < 4; ++j) {
    int lj = l - 3 + j;
    if (lj >= 0)
      acc += ldx(cw, d * 4 + j, bf) * b2f(xin[(size_t)(m - 3 + j) * DI + d]);
  }
  xc[idx] = f2b(acc / (1.f + __expf(-acc)));
}

// ====== chunked selective scan ======
// Phase 1: per-chunk local scan from h=0 -> (a = prod dA, b = h_local)
__global__ __launch_bounds__(256) void scan_p1(
    const bf16* __restrict__ delta, const bf16* __restrict__ xc,
    const bf16* __restrict__ xdbl, const void* __restrict__ A_log,
    float* __restrict__ ca, float* __restrict__ cb,
    const int* __restrict__ flagp) {
  int bf = flagp[0];
  int t = threadIdx.x;
  int n = t & 15, dl = t >> 4;
  int bx = blockIdx.x, c = blockIdx.y;
  int b = bx / NDB, dblk = bx % NDB;
  int d = dblk * 16 + dl;
  float An = -__expf(ldx(A_log, d * DS + n, bf));
  float h = 0.f, ap = 1.f;
  size_t base = (size_t)b * Ll + c * CL;
  for (int l0 = 0; l0 < CL; l0 += 4) {
    float dv[4], xcv[4], Bv[4];
#pragma unroll
    for (int j = 0; j < 4; ++j) {
      size_t row = base + l0 + j;
      dv[j] = b2f(delta[row * DI + d]);
      xcv[j] = b2f(xc[row * DI + d]);
      Bv[j] = b2f(xdbl[row * XD + RK + n]);
    }
#pragma unroll
    for (int j = 0; j < 4; ++j) {
      float dA = __expf(dv[j] * An);
      h = dA * h + dv[j] * Bv[j] * xcv[j];
      ap *= dA;
    }
  }
  size_t ci = ((size_t)(b * NC + c) * NDB + dblk) * 256 + t;
  ca[ci] = ap;
  cb[ci] = h;
}

// Phase 2: sequential scan over chunk carries -> h_init per chunk
__global__ __launch_bounds__(256) void scan_p2(
    const float* __restrict__ ca, float* __restrict__ cb) {
  int t = threadIdx.x;
  int bx = blockIdx.x;
  int b = bx / NDB, dblk = bx % NDB;
  size_t base = ((size_t)b * NC * NDB + dblk) * 256 + t;
  const size_t cs = (size_t)NDB * 256;
  float av[NC], bv[NC];
#pragma unroll
  for (int c = 0; c < NC; ++c) {
    av[c] = ca[base + c * cs];
    bv[c] = cb[base + c * cs];
  }
  float h = 0.f;
#pragma unroll
  for (int c = 0; c < NC; ++c) {
    cb[base + c * cs] = h;
    h = av[c] * h + bv[c];
  }
}

// Phase 3: recompute local scan from h_init, reduce over n, gate, emit y.
__global__ __launch_bounds__(256) void scan_p3(
    bf16* dy, const bf16* __restrict__ xc,
    const bf16* __restrict__ xdbl, const bf16* __restrict__ z,
    const void* __restrict__ A_log, const void* __restrict__ Dp,
    const float* __restrict__ cb, const int* __restrict__ flagp) {
  int bf = flagp[0];
  int t = threadIdx.x;
  int n = t & 15, dl = t >> 4;
  int bx = blockIdx.x, c = blockIdx.y;
  int b = bx / NDB, dblk = bx % NDB;
  int d = dblk * 16 + dl;
  float An = -__expf(ldx(A_log, d * DS + n, bf));
  float Dv = ldx(Dp, d, bf);
  size_t ci = ((size_t)(b * NC + c) * NDB + dblk) * 256 + t;
  float h = cb[ci];
  size_t base = (size_t)b * Ll + c * CL;
  for (int l0 = 0; l0 < CL; l0 += 4) {
    float dv[4], xcv[4], Bv[4], Cv[4], zv[4];
#pragma unroll
    for (int j = 0; j < 4; ++j) {
      size_t row = base + l0 + j;
      dv[j] = b2f(dy[row * DI + d]);
      xcv[j] = b2f(xc[row * DI + d]);
      Bv[j] = b2f(xdbl[row * XD + RK + n]);
      Cv[j] = b2f(xdbl[row * XD + RK + DS + n]);
      zv[j] = b2f(z[row * DI + d]);
    }
#pragma unroll
    for (int j = 0; j < 4; ++j) {
      float dA = __expf(dv[j] * An);
      h = dA * h + dv[j] * Bv[j] * xcv[j];
      float contrib = h * Cv[j];
      contrib += __shfl_xor(contrib, 1, 16);
      contrib += __shfl_xor(contrib, 2, 16);
      contrib += __shfl_xor(contrib, 4, 16);
      contrib += __shfl_xor(contrib, 8, 16);
      if (n == 0) {
        float yv = (contrib + xcv[j] * Dv) * (zv[j] / (1.f + __expf(-zv[j])));
        dy[(base + l0 + j) * DI + d] = f2b(yv);
      }
    }
  }
}

}  // namespace

extern "C" void kernel_launch(void* const* d_in, const int* in_sizes, int n_in,
                              void* d_out, int out_size, void* d_ws, size_t ws_size,
                              hipStream_t stream) {
  const void* x        = d_in[0];
  const void* in_proj  = d_in[1];
  const void* conv_w   = d_in[2];
  const void* conv_b   = d_in[3];
  const void* x_proj   = d_in[4];
  const void* dt_proj  = d_in[5];
  const void* dt_b     = d_in[6];
  const void* A_log    = d_in[7];
  const void* Dp       = d_in[8];
  const void* out_proj = d_in[9];
  const void* ln_w     = d_in[10];
  const void* ln_b     = d_in[11];
  float* out = (float*)d_out;  // reference output dtype: float32

  // ws layout (~51 MB): flag | xn (reused as carry_a) | buf1 | z | xc | xdbl | carry_b
  char* wsc = (char*)d_ws;
  int* flag = (int*)wsc;
  bf16* xn   = (bf16*)(wsc + 256);             // [4096,768]
  bf16* buf1 = xn + (size_t)Mrows * DM;        // [4096,1536]: xin -> delta -> y
  bf16* z    = buf1 + (size_t)Mrows * DI;
  bf16* xc   = z + (size_t)Mrows * DI;
  bf16* xdbl = xc + (size_t)Mrows * DI;        // [4096,80]
  float* carry_b = (float*)(xdbl + (size_t)Mrows * XD);
  float* carry_a = (float*)xn;  // xn dead after in_proj GEMMs

  // 0. detect input dtype (bf16 vs f32)
  detect_kernel<<<1, 64, 0, stream>>>((const unsigned int*)x, flag);
  // 1. layernorm -> xn (bf16)
  ln_kernel<<<Mrows, 256, 0, stream>>>(x, ln_w, ln_b, xn, flag);
  // 2a. xin = xn @ in_proj[0:DI]^T   -> buf1
  gemm_mf<3><<<dim3(DI / 128, Mrows / 128), 256, 0, stream>>>(
      Mrows, DI, DM, xn, DM, in_proj, DM, 0, buf1, DI, nullptr, flag);
  // 2b. z = xn @ in_proj[DI:2*DI]^T
  gemm_mf<3><<<dim3(DI / 128, Mrows / 128), 256, 0, stream>>>(
      Mrows, DI, DM, xn, DM, in_proj, DM, (size_t)DI * DM, z, DI, nullptr, flag);
  // 3. conv + silu: buf1(xin) -> xc
  conv_silu_kernel<<<(Mrows * DI) / 256, 256, 0, stream>>>(buf1, conv_w, conv_b, xc, flag);
  // 4. x_dbl = xc @ x_proj^T  [4096, 80]
  gemm_mf<3><<<dim3(1, Mrows / 128), 256, 0, stream>>>(
      Mrows, XD, DI, xc, DI, x_proj, DI, 0, xdbl, XD, nullptr, flag);
  // 5. delta = softplus(x_dbl[:, :48] @ dt_proj^T + dt_b) -> buf1
  gemm_mf<1><<<dim3(DI / 128, Mrows / 128), 256, 0, stream>>>(
      Mrows, DI, RK, xdbl, XD, dt_proj, RK, 0, buf1, DI, dt_b, flag);
  // 6. chunked selective scan (P1 local, P2 carry, P3 emit) in buf1
  scan_p1<<<dim3(Bb * NDB, NC), 256, 0, stream>>>(
      buf1, xc, xdbl, A_log, carry_a, carry_b, flag);
  scan_p2<<<Bb * NDB, 256, 0, stream>>>(carry_a, carry_b);
  scan_p3<<<dim3(Bb * NDB, NC), 256, 0, stream>>>(
      buf1, xc, xdbl, z, A_log, Dp, carry_b, flag);
  // 7. out = y @ out_proj^T + x (residual), FLOAT out
  gemm_mf<2><<<dim3(DM / 128, Mrows / 128), 256, 0, stream>>>(
      Mrows, DM, DI, buf1, DI, out_proj, DI, 0, out, DM, x, flag);
}

// Round 7
// 471.139 us; speedup vs baseline: 3.0084x; 1.1420x over previous
//
#include <hip/hip_runtime.h>
#include <hip/hip_bf16.h>
#include <math.h>

namespace {

typedef __hip_bfloat16 bf16;
typedef unsigned short u16;
typedef __bf16 bf8v __attribute__((ext_vector_type(8)));
typedef float f4v __attribute__((ext_vector_type(4)));
typedef short s8v __attribute__((ext_vector_type(8)));
typedef u16 u4v __attribute__((ext_vector_type(4)));

constexpr int Bb = 2;
constexpr int Ll = 2048;
constexpr int DM = 768;
constexpr int DI = 1536;          // 2*768
constexpr int DS = 16;
constexpr int RK = 48;
constexpr int XD = RK + 2 * DS;   // 80
constexpr int Mrows = Bb * Ll;    // 4096
constexpr int NC = 32;            // scan chunks
constexpr int CL = Ll / NC;       // 64 steps per chunk
constexpr int NDB = DI / 16;      // 96 d-blocks

__device__ inline float b2f(bf16 v) { return __bfloat162float(v); }
__device__ inline bf16 f2b(float v) { return __float2bfloat16(v); }

union BfBits { bf16 h; u16 u; };
__device__ inline u16 f2u(float v) {
  BfBits bb; bb.h = __float2bfloat16(v); return bb.u;
}

// Swizzled LDS index (u16 units). Row stride 32 elems (64B), XOR row-low-3
// into bits 3-5 -> frag reads are 2-way (free) instead of 8-way conflicted.
__device__ inline int sidx(int row, int col) {
  return (row * 32 + col) ^ ((row & 7) << 3);
}

// Load element i of an EXTERNAL input tensor (dtype runtime-detected).
__device__ inline float ldx(const void* p, size_t i, int bf) {
  if (bf) return __bfloat162float(((const bf16*)p)[i]);
  return ((const float*)p)[i];
}

// ---- dtype probe: do low 16 bits of words look like bf16 values? ----
__global__ void detect_kernel(const unsigned int* __restrict__ xw,
                              int* __restrict__ flag) {
  int t = threadIdx.x;  // 64 lanes
  unsigned int w = xw[t];
  unsigned int lo = w & 0xFFFFu;
  unsigned int ef = (lo >> 7) & 0xFFu;
  bool plaus = (lo == 0u) || (ef >= 104u && ef <= 136u);
  unsigned long long m = __ballot(plaus);
  if (t == 0) flag[0] = (__popcll(m) >= 48) ? 1 : 0;
}

// ---------------- LayerNorm: one block per row of 768, bf16 out -------
__global__ __launch_bounds__(256) void ln_kernel(
    const void* __restrict__ x, const void* __restrict__ w,
    const void* __restrict__ b, bf16* __restrict__ xn,
    const int* __restrict__ flagp) {
  int bf = flagp[0];
  int row = blockIdx.x;
  int t = threadIdx.x;
  float v[3];
  float s = 0.f, ss = 0.f;
#pragma unroll
  for (int i = 0; i < 3; ++i) {
    v[i] = ldx(x, (size_t)row * DM + t + i * 256, bf);
    s += v[i];
    ss += v[i] * v[i];
  }
#pragma unroll
  for (int off = 32; off; off >>= 1) {
    s += __shfl_down(s, off);
    ss += __shfl_down(ss, off);
  }
  __shared__ float sb[4], ssb[4];
  int wid = t >> 6, lid = t & 63;
  if (lid == 0) { sb[wid] = s; ssb[wid] = ss; }
  __syncthreads();
  if (t == 0) {
    sb[0] = sb[0] + sb[1] + sb[2] + sb[3];
    ssb[0] = ssb[0] + ssb[1] + ssb[2] + ssb[3];
  }
  __syncthreads();
  float mu = sb[0] * (1.f / DM);
  float var = ssb[0] * (1.f / DM) - mu * mu;
  float rs = rsqrtf(var + 1e-5f);
#pragma unroll
  for (int i = 0; i < 3; ++i) {
    int c = t + i * 256;
    xn[(size_t)row * DM + c] =
        f2b((v[i] - mu) * rs * ldx(w, c, bf) + ldx(b, c, bf));
  }
}

// ---- MFMA GEMM: C[M,N] = A[M,K](bf16) * B[N,K](external)^T ----------
// BM x 128 tile, BK=32, 4 waves (2x2), double-buffered swizzled LDS,
// one barrier per K-step, global prefetch in regs.
// EPI: 1 = softplus(acc + bias[n]) -> bf16;
//      2 = acc + resid -> FLOAT out; 3 = plain bf16;
//      4 = split store: col<DI -> Cv, else -> Cv2 (both [*,DI] bf16).
template <int EPI, int BM>
__global__ __launch_bounds__(256, 3) void gemm_mf(
    int M, int N, int K,
    const bf16* __restrict__ A, int lda,
    const void* __restrict__ Bw, int ldb, size_t boff,
    void* __restrict__ Cv, void* __restrict__ Cv2, int ldc,
    const void* __restrict__ extra,
    const int* __restrict__ flagp) {
  int bf = flagp[0];
  constexpr int NCH_A = BM / 64;
  constexpr int FI = BM / 32;    // frag rows per wave
  __shared__ u16 As[2][BM * 32];
  __shared__ u16 Bs[2][128 * 32];
  int tid = threadIdx.x;
  int l = tid & 63, w = tid >> 6;
  int wr = w >> 1, wc = w & 1;
  int m0 = blockIdx.y * BM, n0 = blockIdx.x * 128;
  int lr = l & 15, lk = (l >> 4) * 8;
  f4v acc[FI][4] = {};

  // staging thread map
  int arow = tid >> 2;           // 0..63 (+c*64)
  int akc = (tid & 3) * 8;       // 0,8,16,24
  int brow = tid >> 3;           // 0..31 (+c*32)
  int bq = (tid & 7) * 4;        // 0,4,..,28

  s8v aReg[NCH_A];
  u4v bReg[4];

  auto loadAB = [&](int k0) {
#pragma unroll
    for (int c = 0; c < NCH_A; ++c) {
      int gk = k0 + akc;
      s8v v = {};
      if (gk < K)
        v = *(const s8v*)(A + (size_t)(m0 + arow + c * 64) * lda + gk);
      aReg[c] = v;
    }
#pragma unroll
    for (int c = 0; c < 4; ++c) {
      int row = brow + c * 32;
      int gn = n0 + row, gk = k0 + bq;
      u4v v = {};
      if (gn < N && gk < K) {
        size_t bi = boff + (size_t)gn * ldb + gk;
        if (!bf) {
          float4 f = *(const float4*)((const float*)Bw + bi);
          v[0] = f2u(f.x); v[1] = f2u(f.y); v[2] = f2u(f.z); v[3] = f2u(f.w);
        } else {
          v = *(const u4v*)((const u16*)Bw + bi);
        }
      }
      bReg[c] = v;
    }
  };
  auto writeAB = [&](int buf) {
#pragma unroll
    for (int c = 0; c < NCH_A; ++c)
      *(s8v*)&As[buf][sidx(arow + c * 64, akc)] = aReg[c];
#pragma unroll
    for (int c = 0; c < 4; ++c)
      *(u4v*)&Bs[buf][sidx(brow + c * 32, bq)] = bReg[c];
  };

  loadAB(0);
  writeAB(0);
  int nt = (K + 31) / 32;
  for (int t = 0; t < nt; ++t) {
    int cur = t & 1;
    if (t + 1 < nt) loadAB((t + 1) * 32);   // prefetch next tile -> regs
    __syncthreads();                         // buf[cur] writes visible
    bf8v af[FI], bfv[4];
#pragma unroll
    for (int i = 0; i < FI; ++i)
      af[i] = *(const bf8v*)&As[cur][sidx(wr * (BM / 2) + i * 16 + lr, lk)];
#pragma unroll
    for (int j = 0; j < 4; ++j)
      bfv[j] = *(const bf8v*)&Bs[cur][sidx(wc * 64 + j * 16 + lr, lk)];
#pragma unroll
    for (int i = 0; i < FI; ++i)
#pragma unroll
      for (int j = 0; j < 4; ++j)
        acc[i][j] = __builtin_amdgcn_mfma_f32_16x16x32_bf16(
            af[i], bfv[j], acc[i][j], 0, 0, 0);
    if (t + 1 < nt) writeAB(cur ^ 1);        // fill other buffer
  }

  // epilogue: lane l covers col lr, rows (l>>4)*4 + r per fragment
  int lq = l >> 4;
#pragma unroll
  for (int i = 0; i < FI; ++i) {
#pragma unroll
    for (int j = 0; j < 4; ++j) {
      int nn = n0 + wc * 64 + j * 16 + lr;
      if (nn >= N) continue;
#pragma unroll
      for (int r = 0; r < 4; ++r) {
        int m = m0 + wr * (BM / 2) + i * 16 + lq * 4 + r;
        float v = acc[i][j][r];
        size_t ci = (size_t)m * ldc + nn;
        if (EPI == 1) {
          float tt = v + ldx(extra, nn, bf);
          float sp = (tt > 20.f) ? tt : log1pf(__expf(tt));
          ((bf16*)Cv)[ci] = f2b(sp);
        } else if (EPI == 2) {
          ((float*)Cv)[ci] = v + ldx(extra, ci, bf);
        } else if (EPI == 4) {
          if (nn < DI) ((bf16*)Cv)[(size_t)m * DI + nn] = f2b(v);
          else ((bf16*)Cv2)[(size_t)m * DI + nn - DI] = f2b(v);
        } else {
          ((bf16*)Cv)[ci] = f2b(v);
        }
      }
    }
  }
}

// ---------------- depthwise causal conv (d_conv=4) + bias + SiLU ------
__global__ __launch_bounds__(256) void conv_silu_kernel(
    const bf16* __restrict__ xin, const void* __restrict__ cw,
    const void* __restrict__ cb, bf16* __restrict__ xc,
    const int* __restrict__ flagp) {
  int bf = flagp[0];
  int idx = blockIdx.x * 256 + threadIdx.x;
  if (idx >= Mrows * DI) return;
  int d = idx % DI;
  int m = idx / DI;
  int l = m % Ll;
  float acc = ldx(cb, d, bf);
#pragma unroll
  for (int j = 0; j < 4; ++j) {
    int lj = l - 3 + j;
    if (lj >= 0)
      acc += ldx(cw, d * 4 + j, bf) * b2f(xin[(size_t)(m - 3 + j) * DI + d]);
  }
  xc[idx] = f2b(acc / (1.f + __expf(-acc)));
}

// ====== chunked selective scan ======
// Phase 1: per-chunk local scan from h=0 -> (a = prod dA, b = h_local)
__global__ __launch_bounds__(256) void scan_p1(
    const bf16* __restrict__ delta, const bf16* __restrict__ xc,
    const bf16* __restrict__ xdbl, const void* __restrict__ A_log,
    float* __restrict__ ca, float* __restrict__ cb,
    const int* __restrict__ flagp) {
  int bf = flagp[0];
  int t = threadIdx.x;
  int n = t & 15, dl = t >> 4;
  int bx = blockIdx.x, c = blockIdx.y;
  int b = bx / NDB, dblk = bx % NDB;
  int d = dblk * 16 + dl;
  float An = -__expf(ldx(A_log, d * DS + n, bf));
  float h = 0.f, ap = 1.f;
  size_t base = (size_t)b * Ll + c * CL;
  for (int l0 = 0; l0 < CL; l0 += 4) {
    float dv[4], xcv[4], Bv[4];
#pragma unroll
    for (int j = 0; j < 4; ++j) {
      size_t row = base + l0 + j;
      dv[j] = b2f(delta[row * DI + d]);
      xcv[j] = b2f(xc[row * DI + d]);
      Bv[j] = b2f(xdbl[row * XD + RK + n]);
    }
#pragma unroll
    for (int j = 0; j < 4; ++j) {
      float dA = __expf(dv[j] * An);
      h = dA * h + dv[j] * Bv[j] * xcv[j];
      ap *= dA;
    }
  }
  size_t ci = ((size_t)(b * NC + c) * NDB + dblk) * 256 + t;
  ca[ci] = ap;
  cb[ci] = h;
}

// Phase 2: sequential scan over chunk carries -> h_init per chunk
__global__ __launch_bounds__(256) void scan_p2(
    const float* __restrict__ ca, float* __restrict__ cb) {
  int t = threadIdx.x;
  int bx = blockIdx.x;
  int b = bx / NDB, dblk = bx % NDB;
  size_t base = ((size_t)b * NC * NDB + dblk) * 256 + t;
  const size_t cs = (size_t)NDB * 256;
  float av[NC], bv[NC];
#pragma unroll
  for (int c = 0; c < NC; ++c) {
    av[c] = ca[base + c * cs];
    bv[c] = cb[base + c * cs];
  }
  float h = 0.f;
#pragma unroll
  for (int c = 0; c < NC; ++c) {
    cb[base + c * cs] = h;
    h = av[c] * h + bv[c];
  }
}

// Phase 3: recompute local scan from h_init, reduce over n, gate, emit y.
__global__ __launch_bounds__(256) void scan_p3(
    bf16* dy, const bf16* __restrict__ xc,
    const bf16* __restrict__ xdbl, const bf16* __restrict__ z,
    const void* __restrict__ A_log, const void* __restrict__ Dp,
    const float* __restrict__ cb, const int* __restrict__ flagp) {
  int bf = flagp[0];
  int t = threadIdx.x;
  int n = t & 15, dl = t >> 4;
  int bx = blockIdx.x, c = blockIdx.y;
  int b = bx / NDB, dblk = bx % NDB;
  int d = dblk * 16 + dl;
  float An = -__expf(ldx(A_log, d * DS + n, bf));
  float Dv = ldx(Dp, d, bf);
  size_t ci = ((size_t)(b * NC + c) * NDB + dblk) * 256 + t;
  float h = cb[ci];
  size_t base = (size_t)b * Ll + c * CL;
  for (int l0 = 0; l0 < CL; l0 += 4) {
    float dv[4], xcv[4], Bv[4], Cv[4], zv[4];
#pragma unroll
    for (int j = 0; j < 4; ++j) {
      size_t row = base + l0 + j;
      dv[j] = b2f(dy[row * DI + d]);
      xcv[j] = b2f(xc[row * DI + d]);
      Bv[j] = b2f(xdbl[row * XD + RK + n]);
      Cv[j] = b2f(xdbl[row * XD + RK + DS + n]);
      zv[j] = b2f(z[row * DI + d]);
    }
#pragma unroll
    for (int j = 0; j < 4; ++j) {
      float dA = __expf(dv[j] * An);
      h = dA * h + dv[j] * Bv[j] * xcv[j];
      float contrib = h * Cv[j];
      contrib += __shfl_xor(contrib, 1, 16);
      contrib += __shfl_xor(contrib, 2, 16);
      contrib += __shfl_xor(contrib, 4, 16);
      contrib += __shfl_xor(contrib, 8, 16);
      if (n == 0) {
        float yv = (contrib + xcv[j] * Dv) * (zv[j] / (1.f + __expf(-zv[j])));
        dy[(base + l0 + j) * DI + d] = f2b(yv);
      }
    }
  }
}

}  // namespace

extern "C" void kernel_launch(void* const* d_in, const int* in_sizes, int n_in,
                              void* d_out, int out_size, void* d_ws, size_t ws_size,
                              hipStream_t stream) {
  const void* x        = d_in[0];
  const void* in_proj  = d_in[1];
  const void* conv_w   = d_in[2];
  const void* conv_b   = d_in[3];
  const void* x_proj   = d_in[4];
  const void* dt_proj  = d_in[5];
  const void* dt_b     = d_in[6];
  const void* A_log    = d_in[7];
  const void* Dp       = d_in[8];
  const void* out_proj = d_in[9];
  const void* ln_w     = d_in[10];
  const void* ln_b     = d_in[11];
  float* out = (float*)d_out;  // reference output dtype: float32

  // ws layout (~51 MB): flag | xn (reused as carry_a) | buf1 | z | xc | xdbl | carry_b
  char* wsc = (char*)d_ws;
  int* flag = (int*)wsc;
  bf16* xn   = (bf16*)(wsc + 256);             // [4096,768]
  bf16* buf1 = xn + (size_t)Mrows * DM;        // [4096,1536]: xin -> delta -> y
  bf16* z    = buf1 + (size_t)Mrows * DI;
  bf16* xc   = z + (size_t)Mrows * DI;
  bf16* xdbl = xc + (size_t)Mrows * DI;        // [4096,80]
  float* carry_b = (float*)(xdbl + (size_t)Mrows * XD);
  float* carry_a = (float*)xn;  // xn dead after in_proj GEMM

  // 0. detect input dtype (bf16 vs f32)
  detect_kernel<<<1, 64, 0, stream>>>((const unsigned int*)x, flag);
  // 1. layernorm -> xn (bf16)
  ln_kernel<<<Mrows, 256, 0, stream>>>(x, ln_w, ln_b, xn, flag);
  // 2. fused in_proj: [xin | z] = xn @ in_proj^T  (N=3072, split store)
  gemm_mf<4, 128><<<dim3(2 * DI / 128, Mrows / 128), 256, 0, stream>>>(
      Mrows, 2 * DI, DM, xn, DM, in_proj, DM, 0, buf1, z, DI, nullptr, flag);
  // 3. conv + silu: buf1(xin) -> xc
  conv_silu_kernel<<<(Mrows * DI) / 256, 256, 0, stream>>>(buf1, conv_w, conv_b, xc, flag);
  // 4. x_dbl = xc @ x_proj^T  [4096, 80]
  gemm_mf<3, 64><<<dim3(1, Mrows / 64), 256, 0, stream>>>(
      Mrows, XD, DI, xc, DI, x_proj, DI, 0, xdbl, nullptr, XD, nullptr, flag);
  // 5. delta = softplus(x_dbl[:, :48] @ dt_proj^T + dt_b) -> buf1
  gemm_mf<1, 128><<<dim3(DI / 128, Mrows / 128), 256, 0, stream>>>(
      Mrows, DI, RK, xdbl, XD, dt_proj, RK, 0, buf1, nullptr, DI, dt_b, flag);
  // 6. chunked selective scan (P1 local, P2 carry, P3 emit) in buf1
  scan_p1<<<dim3(Bb * NDB, NC), 256, 0, stream>>>(
      buf1, xc, xdbl, A_log, carry_a, carry_b, flag);
  scan_p2<<<Bb * NDB, 256, 0, stream>>>(carry_a, carry_b);
  scan_p3<<<dim3(Bb * NDB, NC), 256, 0, stream>>>(
      buf1, xc, xdbl, z, A_log, Dp, carry_b, flag);
  // 7. out = y @ out_proj^T + x (residual), FLOAT out
  gemm_mf<2, 64><<<dim3(DM / 128, Mrows / 64), 256, 0, stream>>>(
      Mrows, DM, DI, buf1, DI, out_proj, DI, 0, out, nullptr, DM, x, flag);
}

// Round 8
// 364.537 us; speedup vs baseline: 3.8881x; 1.2924x over previous
//
#include <hip/hip_runtime.h>
#include <hip/hip_bf16.h>
#include <math.h>

namespace {

typedef __hip_bfloat16 bf16;
typedef unsigned short u16;
typedef __bf16 bf8v __attribute__((ext_vector_type(8)));
typedef float f4v __attribute__((ext_vector_type(4)));
typedef short s8v __attribute__((ext_vector_type(8)));
typedef u16 u4v __attribute__((ext_vector_type(4)));

constexpr int Bb = 2;
constexpr int Ll = 2048;
constexpr int DM = 768;
constexpr int DI = 1536;          // 2*768
constexpr int DS = 16;
constexpr int RK = 48;
constexpr int XD = RK + 2 * DS;   // 80
constexpr int Mrows = Bb * Ll;    // 4096
constexpr int NC = 32;            // scan chunks
constexpr int CL = Ll / NC;       // 64 steps per chunk
constexpr int NDB = DI / 16;      // 96 d-blocks

__device__ inline float b2f(bf16 v) { return __bfloat162float(v); }
__device__ inline bf16 f2b(float v) { return __float2bfloat16(v); }

union BfBits { bf16 h; u16 u; };
__device__ inline u16 f2u(float v) {
  BfBits bb; bb.h = __float2bfloat16(v); return bb.u;
}

// Swizzled LDS index (u16 units). Row stride 32 elems (64B); XOR row-low-3
// into bits 3-5 -> 16-lane frag reads hit 8 bank-quads (2-way = free).
__device__ inline int sidx(int row, int col) {
  return (row * 32 + col) ^ ((row & 7) << 3);
}

// Load element i of an EXTERNAL input tensor (dtype runtime-detected).
__device__ inline float ldx(const void* p, size_t i, int bf) {
  if (bf) return __bfloat162float(((const bf16*)p)[i]);
  return ((const float*)p)[i];
}

// ---- dtype probe: do low 16 bits of words look like bf16 values? ----
__global__ void detect_kernel(const unsigned int* __restrict__ xw,
                              int* __restrict__ flag) {
  int t = threadIdx.x;  // 64 lanes
  unsigned int w = xw[t];
  unsigned int lo = w & 0xFFFFu;
  unsigned int ef = (lo >> 7) & 0xFFu;
  bool plaus = (lo == 0u) || (ef >= 104u && ef <= 136u);
  unsigned long long m = __ballot(plaus);
  if (t == 0) flag[0] = (__popcll(m) >= 48) ? 1 : 0;
}

// ---------------- LayerNorm: one block per row of 768, bf16 out -------
__global__ __launch_bounds__(256) void ln_kernel(
    const void* __restrict__ x, const void* __restrict__ w,
    const void* __restrict__ b, bf16* __restrict__ xn,
    const int* __restrict__ flagp) {
  int bf = flagp[0];
  int row = blockIdx.x;
  int t = threadIdx.x;
  float v[3];
  float s = 0.f, ss = 0.f;
#pragma unroll
  for (int i = 0; i < 3; ++i) {
    v[i] = ldx(x, (size_t)row * DM + t + i * 256, bf);
    s += v[i];
    ss += v[i] * v[i];
  }
#pragma unroll
  for (int off = 32; off; off >>= 1) {
    s += __shfl_down(s, off);
    ss += __shfl_down(ss, off);
  }
  __shared__ float sb[4], ssb[4];
  int wid = t >> 6, lid = t & 63;
  if (lid == 0) { sb[wid] = s; ssb[wid] = ss; }
  __syncthreads();
  if (t == 0) {
    sb[0] = sb[0] + sb[1] + sb[2] + sb[3];
    ssb[0] = ssb[0] + ssb[1] + ssb[2] + ssb[3];
  }
  __syncthreads();
  float mu = sb[0] * (1.f / DM);
  float var = ssb[0] * (1.f / DM) - mu * mu;
  float rs = rsqrtf(var + 1e-5f);
#pragma unroll
  for (int i = 0; i < 3; ++i) {
    int c = t + i * 256;
    xn[(size_t)row * DM + c] =
        f2b((v[i] - mu) * rs * ldx(w, c, bf) + ldx(b, c, bf));
  }
}

// ---- MFMA GEMM: C[M,N] = A[M,K](bf16) * B[N,K](external)^T ----------
// BM x 128 tile, BK=32, 4 waves (2x2), double-buffered swizzled LDS,
// global prefetch in regs, one barrier per K-step.
// Split-K: blockIdx.z selects K-chunk [z*klen, min(K,(z+1)*klen)).
// EPI: 0 = f32 partial store at Cv + z*M*ldc;
//      1 = softplus(acc + bias[n]) -> bf16;
//      4 = split store: col<DI -> Cv, else -> Cv2 (both [*,DI] bf16).
template <int EPI, int BM>
__global__ __launch_bounds__(256, 2) void gemm_mf(
    int M, int N, int K, int klen,
    const bf16* __restrict__ A, int lda,
    const void* __restrict__ Bw, int ldb, size_t boff,
    void* __restrict__ Cv, void* __restrict__ Cv2, int ldc,
    const void* __restrict__ extra,
    const int* __restrict__ flagp) {
  int bf = flagp[0];
  constexpr int NCH_A = BM / 64;
  constexpr int FI = BM / 32;    // A-frags per wave
  __shared__ u16 As[2][BM * 32];
  __shared__ u16 Bs[2][128 * 32];
  int tid = threadIdx.x;
  int l = tid & 63, w = tid >> 6;
  int wr = w >> 1, wc = w & 1;
  int m0 = blockIdx.y * BM, n0 = blockIdx.x * 128;
  int kbeg = blockIdx.z * klen;
  int kend = min(K, kbeg + klen);
  int lr = l & 15, lk = (l >> 4) * 8;
  f4v acc[FI][4] = {};

  // staging thread map
  int arow = tid >> 2;           // 0..63 (+c*64)
  int akc = (tid & 3) * 8;       // 0,8,16,24
  int brow = tid >> 3;           // 0..31 (+c*32)
  int bq = (tid & 7) * 4;        // 0,4,..,28

  s8v aReg[NCH_A];
  u4v bReg[4];

  auto loadAB = [&](int k0) {
#pragma unroll
    for (int c = 0; c < NCH_A; ++c) {
      int gk = k0 + akc;
      s8v v = {};
      if (gk < kend)
        v = *(const s8v*)(A + (size_t)(m0 + arow + c * 64) * lda + gk);
      aReg[c] = v;
    }
#pragma unroll
    for (int c = 0; c < 4; ++c) {
      int row = brow + c * 32;
      int gn = n0 + row, gk = k0 + bq;
      u4v v = {};
      if (gn < N && gk < kend) {
        size_t bi = boff + (size_t)gn * ldb + gk;
        if (!bf) {
          float4 f = *(const float4*)((const float*)Bw + bi);
          v[0] = f2u(f.x); v[1] = f2u(f.y); v[2] = f2u(f.z); v[3] = f2u(f.w);
        } else {
          v = *(const u4v*)((const u16*)Bw + bi);
        }
      }
      bReg[c] = v;
    }
  };
  auto writeAB = [&](int buf) {
#pragma unroll
    for (int c = 0; c < NCH_A; ++c)
      *(s8v*)&As[buf][sidx(arow + c * 64, akc)] = aReg[c];
#pragma unroll
    for (int c = 0; c < 4; ++c)
      *(u4v*)&Bs[buf][sidx(brow + c * 32, bq)] = bReg[c];
  };

  loadAB(kbeg);
  writeAB(0);
  int nt = (kend - kbeg + 31) / 32;
  for (int t = 0; t < nt; ++t) {
    int cur = t & 1;
    if (t + 1 < nt) loadAB(kbeg + (t + 1) * 32);  // prefetch -> regs
    __syncthreads();                              // buf[cur] visible
    bf8v af[FI], bfv[4];
#pragma unroll
    for (int i = 0; i < FI; ++i)
      af[i] = *(const bf8v*)&As[cur][sidx(wr * (BM / 2) + i * 16 + lr, lk)];
#pragma unroll
    for (int j = 0; j < 4; ++j)
      bfv[j] = *(const bf8v*)&Bs[cur][sidx(wc * 64 + j * 16 + lr, lk)];
#pragma unroll
    for (int i = 0; i < FI; ++i)
#pragma unroll
      for (int j = 0; j < 4; ++j)
        acc[i][j] = __builtin_amdgcn_mfma_f32_16x16x32_bf16(
            af[i], bfv[j], acc[i][j], 0, 0, 0);
    if (t + 1 < nt) writeAB(cur ^ 1);
  }

  // epilogue: lane l -> col lr, rows (l>>4)*4 + r per fragment
  int lq = l >> 4;
  size_t pbase = (size_t)blockIdx.z * M * ldc;
#pragma unroll
  for (int i = 0; i < FI; ++i) {
#pragma unroll
    for (int j = 0; j < 4; ++j) {
      int nn = n0 + wc * 64 + j * 16 + lr;
      if (nn >= N) continue;
#pragma unroll
      for (int r = 0; r < 4; ++r) {
        int m = m0 + wr * (BM / 2) + i * 16 + lq * 4 + r;
        float v = acc[i][j][r];
        size_t ci = (size_t)m * ldc + nn;
        if (EPI == 0) {
          ((float*)Cv)[pbase + ci] = v;
        } else if (EPI == 1) {
          float tt = v + ldx(extra, nn, bf);
          float sp = (tt > 20.f) ? tt : log1pf(__expf(tt));
          ((bf16*)Cv)[ci] = f2b(sp);
        } else if (EPI == 4) {
          if (nn < DI) ((bf16*)Cv)[(size_t)m * DI + nn] = f2b(v);
          else ((bf16*)Cv2)[(size_t)m * DI + nn - DI] = f2b(v);
        }
      }
    }
  }
}

// ---- reduce 8 f32 partials -> bf16 xdbl [4096,80] ----
__global__ __launch_bounds__(256) void reduce_xdbl(
    const float* __restrict__ part, bf16* __restrict__ xdbl) {
  int idx = blockIdx.x * 256 + threadIdx.x;
  if (idx >= Mrows * XD) return;
  float s = 0.f;
#pragma unroll
  for (int k = 0; k < 8; ++k) s += part[(size_t)k * Mrows * XD + idx];
  xdbl[idx] = f2b(s);
}

// ---- reduce 2 f32 partials + residual -> f32 out [4096,768] ----
__global__ __launch_bounds__(256) void reduce_out(
    const float* __restrict__ part, const void* __restrict__ x,
    float* __restrict__ out, const int* __restrict__ flagp) {
  int bf = flagp[0];
  int idx = blockIdx.x * 256 + threadIdx.x;
  if (idx >= Mrows * DM) return;
  out[idx] = part[idx] + part[(size_t)Mrows * DM + idx] + ldx(x, idx, bf);
}

// ---------------- depthwise causal conv (d_conv=4) + bias + SiLU ------
__global__ __launch_bounds__(256) void conv_silu_kernel(
    const bf16* __restrict__ xin, const void* __restrict__ cw,
    const void* __restrict__ cb, bf16* __restrict__ xc,
    const int* __restrict__ flagp) {
  int bf = flagp[0];
  int idx = blockIdx.x * 256 + threadIdx.x;
  if (idx >= Mrows * DI) return;
  int d = idx % DI;
  int m = idx / DI;
  int l = m % Ll;
  float acc = ldx(cb, d, bf);
#pragma unroll
  for (int j = 0; j < 4; ++j) {
    int lj = l - 3 + j;
    if (lj >= 0)
      acc += ldx(cw, d * 4 + j, bf) * b2f(xin[(size_t)(m - 3 + j) * DI + d]);
  }
  xc[idx] = f2b(acc / (1.f + __expf(-acc)));
}

// ====== chunked selective scan ======
// Phase 1: per-chunk local scan from h=0 -> (a = prod dA, b = h_local)
__global__ __launch_bounds__(256) void scan_p1(
    const bf16* __restrict__ delta, const bf16* __restrict__ xc,
    const bf16* __restrict__ xdbl, const void* __restrict__ A_log,
    float* __restrict__ ca, float* __restrict__ cb,
    const int* __restrict__ flagp) {
  int bf = flagp[0];
  int t = threadIdx.x;
  int n = t & 15, dl = t >> 4;
  int bx = blockIdx.x, c = blockIdx.y;
  int b = bx / NDB, dblk = bx % NDB;
  int d = dblk * 16 + dl;
  float An = -__expf(ldx(A_log, d * DS + n, bf));
  float h = 0.f, ap = 1.f;
  size_t base = (size_t)b * Ll + c * CL;
  for (int l0 = 0; l0 < CL; l0 += 4) {
    float dv[4], xcv[4], Bv[4];
#pragma unroll
    for (int j = 0; j < 4; ++j) {
      size_t row = base + l0 + j;
      dv[j] = b2f(delta[row * DI + d]);
      xcv[j] = b2f(xc[row * DI + d]);
      Bv[j] = b2f(xdbl[row * XD + RK + n]);
    }
#pragma unroll
    for (int j = 0; j < 4; ++j) {
      float dA = __expf(dv[j] * An);
      h = dA * h + dv[j] * Bv[j] * xcv[j];
      ap *= dA;
    }
  }
  size_t ci = ((size_t)(b * NC + c) * NDB + dblk) * 256 + t;
  ca[ci] = ap;
  cb[ci] = h;
}

// Phase 2: sequential scan over chunk carries -> h_init per chunk
__global__ __launch_bounds__(256) void scan_p2(
    const float* __restrict__ ca, float* __restrict__ cb) {
  int t = threadIdx.x;
  int bx = blockIdx.x;
  int b = bx / NDB, dblk = bx % NDB;
  size_t base = ((size_t)b * NC * NDB + dblk) * 256 + t;
  const size_t cs = (size_t)NDB * 256;
  float av[NC], bv[NC];
#pragma unroll
  for (int c = 0; c < NC; ++c) {
    av[c] = ca[base + c * cs];
    bv[c] = cb[base + c * cs];
  }
  float h = 0.f;
#pragma unroll
  for (int c = 0; c < NC; ++c) {
    cb[base + c * cs] = h;
    h = av[c] * h + bv[c];
  }
}

// Phase 3: recompute local scan from h_init, reduce over n, gate, emit y.
__global__ __launch_bounds__(256) void scan_p3(
    bf16* dy, const bf16* __restrict__ xc,
    const bf16* __restrict__ xdbl, const bf16* __restrict__ z,
    const void* __restrict__ A_log, const void* __restrict__ Dp,
    const float* __restrict__ cb, const int* __restrict__ flagp) {
  int bf = flagp[0];
  int t = threadIdx.x;
  int n = t & 15, dl = t >> 4;
  int bx = blockIdx.x, c = blockIdx.y;
  int b = bx / NDB, dblk = bx % NDB;
  int d = dblk * 16 + dl;
  float An = -__expf(ldx(A_log, d * DS + n, bf));
  float Dv = ldx(Dp, d, bf);
  size_t ci = ((size_t)(b * NC + c) * NDB + dblk) * 256 + t;
  float h = cb[ci];
  size_t base = (size_t)b * Ll + c * CL;
  for (int l0 = 0; l0 < CL; l0 += 4) {
    float dv[4], xcv[4], Bv[4], Cv[4], zv[4];
#pragma unroll
    for (int j = 0; j < 4; ++j) {
      size_t row = base + l0 + j;
      dv[j] = b2f(dy[row * DI + d]);
      xcv[j] = b2f(xc[row * DI + d]);
      Bv[j] = b2f(xdbl[row * XD + RK + n]);
      Cv[j] = b2f(xdbl[row * XD + RK + DS + n]);
      zv[j] = b2f(z[row * DI + d]);
    }
#pragma unroll
    for (int j = 0; j < 4; ++j) {
      float dA = __expf(dv[j] * An);
      h = dA * h + dv[j] * Bv[j] * xcv[j];
      float contrib = h * Cv[j];
      contrib += __shfl_xor(contrib, 1, 16);
      contrib += __shfl_xor(contrib, 2, 16);
      contrib += __shfl_xor(contrib, 4, 16);
      contrib += __shfl_xor(contrib, 8, 16);
      if (n == 0) {
        float yv = (contrib + xcv[j] * Dv) * (zv[j] / (1.f + __expf(-zv[j])));
        dy[(base + l0 + j) * DI + d] = f2b(yv);
      }
    }
  }
}

}  // namespace

extern "C" void kernel_launch(void* const* d_in, const int* in_sizes, int n_in,
                              void* d_out, int out_size, void* d_ws, size_t ws_size,
                              hipStream_t stream) {
  const void* x        = d_in[0];
  const void* in_proj  = d_in[1];
  const void* conv_w   = d_in[2];
  const void* conv_b   = d_in[3];
  const void* x_proj   = d_in[4];
  const void* dt_proj  = d_in[5];
  const void* dt_b     = d_in[6];
  const void* A_log    = d_in[7];
  const void* Dp       = d_in[8];
  const void* out_proj = d_in[9];
  const void* ln_w     = d_in[10];
  const void* ln_b     = d_in[11];
  float* out = (float*)d_out;  // reference output dtype: float32

  // ws layout (~51 MB): flag | xn | buf1 | z | xc | xdbl | carry_b
  char* wsc = (char*)d_ws;
  int* flag = (int*)wsc;
  bf16* xn   = (bf16*)(wsc + 256);             // [4096,768]
  bf16* buf1 = xn + (size_t)Mrows * DM;        // [4096,1536]: xin->delta->y
  bf16* z    = buf1 + (size_t)Mrows * DI;
  bf16* xc   = z + (size_t)Mrows * DI;
  bf16* xdbl = xc + (size_t)Mrows * DI;        // [4096,80]
  float* carry_b = (float*)(xdbl + (size_t)Mrows * XD);
  float* carry_a = (float*)xn;      // xn dead after in_proj GEMM
  // x_proj partials [8][4096][80] f32 = 10.5 MB -> buf1 region (xin dead
  // after conv, delta written only after reduce_xdbl+dt GEMM)
  float* part8 = (float*)buf1;
  // out_proj partials [2][4096][768] f32 = 25.17 MB -> z+xc region
  // (both dead after scan_p3)
  float* part2 = (float*)z;

  // 0. detect input dtype (bf16 vs f32)
  detect_kernel<<<1, 64, 0, stream>>>((const unsigned int*)x, flag);
  // 1. layernorm -> xn (bf16)
  ln_kernel<<<Mrows, 256, 0, stream>>>(x, ln_w, ln_b, xn, flag);
  // 2. fused in_proj: [xin | z] = xn @ in_proj^T  (N=3072, split store)
  gemm_mf<4, 128><<<dim3(2 * DI / 128, Mrows / 128, 1), 256, 0, stream>>>(
      Mrows, 2 * DI, DM, DM, xn, DM, in_proj, DM, 0, buf1, z, DI, nullptr, flag);
  // 3. conv + silu: buf1(xin) -> xc
  conv_silu_kernel<<<(Mrows * DI) / 256, 256, 0, stream>>>(buf1, conv_w, conv_b, xc, flag);
  // 4. x_dbl = xc @ x_proj^T  [4096, 80], split-K=8 -> part8 -> xdbl
  gemm_mf<0, 64><<<dim3(1, Mrows / 64, 8), 256, 0, stream>>>(
      Mrows, XD, DI, DI / 8, xc, DI, x_proj, DI, 0, part8, nullptr, XD, nullptr, flag);
  reduce_xdbl<<<(Mrows * XD + 255) / 256, 256, 0, stream>>>(part8, xdbl);
  // 5. delta = softplus(x_dbl[:, :48] @ dt_proj^T + dt_b) -> buf1
  gemm_mf<1, 64><<<dim3(DI / 128, Mrows / 64, 1), 256, 0, stream>>>(
      Mrows, DI, RK, RK, xdbl, XD, dt_proj, RK, 0, buf1, nullptr, DI, dt_b, flag);
  // 6. chunked selective scan (P1 local, P2 carry, P3 emit) in buf1
  scan_p1<<<dim3(Bb * NDB, NC), 256, 0, stream>>>(
      buf1, xc, xdbl, A_log, carry_a, carry_b, flag);
  scan_p2<<<Bb * NDB, 256, 0, stream>>>(carry_a, carry_b);
  scan_p3<<<dim3(Bb * NDB, NC), 256, 0, stream>>>(
      buf1, xc, xdbl, z, A_log, Dp, carry_b, flag);
  // 7. out_proj split-K=2 -> part2, then + residual -> f32 out
  gemm_mf<0, 64><<<dim3(DM / 128, Mrows / 64, 2), 256, 0, stream>>>(
      Mrows, DM, DI, DI / 2, buf1, DI, out_proj, DI, 0, part2, nullptr, DM, nullptr, flag);
  reduce_out<<<(Mrows * DM + 255) / 256, 256, 0, stream>>>(part2, x, out, flag);
}